// Round 6
// baseline (222.572 us; speedup 1.0000x reference)
//
#include <hip/hip_runtime.h>

// MetaUpSampler via bf16 MFMA — round 6.
// GEMM view: out2d[m][po] = sum_{tap,c} x[n,c,h+di-1,w+dj-1] * lwb[tap][c][po]
// Stage A: MLP -> lwb bf16 [tap][po][c]. Grid 7x16 (one p per block-row),
//   one W2 column per thread, coalesced loads, unroll 16. 112 blocks.
// Stage B: 64-wide x 4-row tile per block (4x R5's M): 3 waves, po-tile each.
//   - 6 input rows staged (2/wave), coalesced+transposed, XOR-swizzled [r][j][c]
//   - 288 MFMAs/wave: sunk B-loads amortize over 16 m-tiles (R5: only 4)
//   - epilogue transposes D through LDS (reused) -> full-line float4 stores

#define HH   192
#define WWD  192
#define SS   4
#define OC   3
#define PO   48
#define HID  256
#define W2LD 1728

typedef short  bf16x8 __attribute__((ext_vector_type(8)));
typedef float  f32x4  __attribute__((ext_vector_type(4)));

static __device__ __forceinline__ short f2bf(float f) {
    unsigned u = __float_as_uint(f);
    unsigned r = (u + 0x7fffu + ((u >> 16) & 1u)) >> 16;   // RNE
    return (short)r;
}

// ---------------- Stage A: MLP -> dynamic weights, bf16, [tap][po][c] -------
// Grid: dim3(7,16) x 256 threads. blockIdx.y = p; thread = one W2 column.
__global__ __launch_bounds__(256) void lw_kernel(
        const float* __restrict__ W1, const float* __restrict__ b1,
        const float* __restrict__ W2, const float* __restrict__ b2,
        short* __restrict__ lwb) {
    __shared__ float hlds[HID];
    const int tid = threadIdx.x;       // == hidden index h for the MLP part
    const int p   = blockIdx.y;
    {
        const float pi = (float)(p >> 2) * 0.25f;
        const float pj = (float)(p & 3) * 0.25f;
        const float v = 0.25f * W1[tid] + pi * W1[HID + tid] + pj * W1[2 * HID + tid]
                      + b1[tid];
        hlds[tid] = v > 0.f ? v : 0.f;
    }
    __syncthreads();

    const int col = blockIdx.x * 256 + tid;   // 0..1791 (guard at 1728)
    if (col < W2LD) {
        float a = 0.f;
#pragma unroll 16
        for (int h = 0; h < HID; ++h)
            a += hlds[h] * W2[h * W2LD + col];   // coalesced 4B + LDS broadcast
        const int o = col % 3, kc = col / 3;
        const int tap = kc % 9, c = kc / 9;
        lwb[(tap * PO + p * 3 + o) * 64 + c] = f2bf(a + b2[col]);
    }
}

// ---------------- Stage B: MFMA dynamic conv --------------------------------
// Block: 64 pixels x 4 rows x 48 po. 3 waves (192 thr), po-tile per wave.
__global__ __launch_bounds__(192, 3) void meta_up_mfma(
        const float* __restrict__ x, const short* __restrict__ lwb,
        float* __restrict__ out) {
    __shared__ __align__(16) short smem[6 * 66 * 64];   // 50,688 B
    short* xlds = smem;                    // [r 0..5][j 0..65][c], XOR'd 16B blocks
    float* obuf = (float*)smem;            // reused post-MFMA: 4 x 12 x 260 floats

    // XCD-band swizzle: 576 tiles = 8 XCDs x 72; contiguous (n,hb) per XCD.
    const int tile = (blockIdx.x & 7) * 72 + (blockIdx.x >> 3);
    const int n   = tile / (48 * 3);
    const int rem = tile % (48 * 3);
    const int hb  = rem / 3;               // 4-row band: rows 4*hb .. 4*hb+3
    const int wch = rem % 3;
    const int h0  = hb * 4;
    const int w0  = wch * 64;

    const int tid  = threadIdx.x;
    const int lane = tid & 63, wv = tid >> 6;
    const int quad = lane >> 4, l15 = lane & 15;

    // B fragments (compiler may keep in regs or sink; both OK — L2-hot,
    // amortized over 16 m-tiles per fragment).
    bf16x8 Bfrag[18];
#pragma unroll
    for (int tap = 0; tap < 9; ++tap)
#pragma unroll
        for (int kc2 = 0; kc2 < 2; ++kc2)
            Bfrag[tap * 2 + kc2] = *(const bf16x8*)
                &lwb[(tap * PO + wv * 16 + l15) * 64 + kc2 * 32 + quad * 8];

    // Stage 6 rows (gr = h0-1 .. h0+4), 2 per wave. Lane = column j (coalesced);
    // gather 8 channels -> one ds_write_b128.
#pragma unroll
    for (int rr2 = 0; rr2 < 2; ++rr2) {
        const int r  = wv * 2 + rr2;               // 0..5
        const int gr = h0 - 1 + r;
        const bool rok = (unsigned)gr < (unsigned)HH;
        const int gc  = w0 - 1 + lane;
        const bool cok = rok && ((unsigned)gc < (unsigned)WWD);
        const float* __restrict__ xr =
            x + ((size_t)n * 64 * HH + (size_t)(rok ? gr : 0)) * WWD + (cok ? gc : 0);
#pragma unroll
        for (int cb = 0; cb < 8; ++cb) {
            bf16x8 pk;
#pragma unroll
            for (int cc = 0; cc < 8; ++cc) {
                const float vv = cok ? xr[(size_t)(cb * 8 + cc) * HH * WWD] : 0.f;
                pk[cc] = f2bf(vv);
            }
            *(bf16x8*)&xlds[(r * 66 + lane) * 64 + ((cb ^ (lane & 7)) << 3)] = pk;
        }
        if (lane < 16) {                 // tail columns j = 64, 65
            const int jt = 64 + (lane >> 3);
            const int cb = lane & 7;
            const int gc2 = w0 - 1 + jt;
            const bool cok2 = rok && ((unsigned)gc2 < (unsigned)WWD);
            bf16x8 pk;
#pragma unroll
            for (int cc = 0; cc < 8; ++cc) {
                const float vv = cok2 ?
                    x[((size_t)(n * 64 + cb * 8 + cc) * HH + gr) * WWD + gc2] : 0.f;
                pk[cc] = f2bf(vv);
            }
            *(bf16x8*)&xlds[(r * 66 + jt) * 64 + ((cb ^ (jt & 7)) << 3)] = pk;
        }
    }
    __syncthreads();

    // Main loop: 9 taps x 2 K-chunks x (4 rows x 4 m-tiles) = 288 MFMAs/wave.
    f32x4 acc[16];                         // [rr*4 + mt]
#pragma unroll
    for (int i = 0; i < 16; ++i) acc[i] = (f32x4){0.f, 0.f, 0.f, 0.f};

#pragma unroll
    for (int tap = 0; tap < 9; ++tap) {
        const int di = tap / 3, dj = tap % 3;
#pragma unroll
        for (int kc2 = 0; kc2 < 2; ++kc2) {
            const bf16x8 b = Bfrag[tap * 2 + kc2];
#pragma unroll
            for (int rr = 0; rr < 4; ++rr) {
#pragma unroll
                for (int mt = 0; mt < 4; ++mt) {
                    const int col = mt * 16 + l15 + dj;        // 0..65
                    const int blk = (kc2 * 4 + quad) ^ (col & 7);
                    bf16x8 a = *(const bf16x8*)
                        &xlds[((rr + di) * 66 + col) * 64 + (blk << 3)];
                    acc[rr * 4 + mt] =
                        __builtin_amdgcn_mfma_f32_16x16x32_bf16(a, b, acc[rr * 4 + mt], 0, 0, 0);
                }
            }
        }
    }

    // Epilogue: transpose D through LDS -> full-line coalesced stores.
    __syncthreads();                       // all xlds reads complete
    {
        const int po = wv * 16 + l15;
        const int o  = po % 3;
        const int p  = po / 3;
        const int si = p >> 2, sj = p & 3;
        const int osi = o * 4 + si;
#pragma unroll
        for (int rr = 0; rr < 4; ++rr)
#pragma unroll
            for (int mt = 0; mt < 4; ++mt)
#pragma unroll
                for (int r4 = 0; r4 < 4; ++r4) {
                    const int wl = mt * 16 + quad * 4 + r4;
                    obuf[rr * 3120 + osi * 260 + wl * 4 + sj] = acc[rr * 4 + mt][r4];
                }
    }
    __syncthreads();
    {
        const int osi = tid >> 4;          // 0..11
        const int c16 = tid & 15;
        const int o = osi >> 2, si = osi & 3;
#pragma unroll
        for (int rr = 0; rr < 4; ++rr) {
            const size_t base =
                ((size_t)(n * OC + o) * (SS * HH) + (size_t)(SS * (h0 + rr) + si)) * (SS * WWD)
                + (size_t)(4 * w0) + c16 * 16;
            const float* __restrict__ src = &obuf[rr * 3120 + osi * 260 + c16 * 16];
#pragma unroll
            for (int i = 0; i < 4; ++i)    // 64B contiguous per thread
                *(float4*)&out[base + i * 4] = *(const float4*)&src[i * 4];
        }
    }
}

extern "C" void kernel_launch(void* const* d_in, const int* in_sizes, int n_in,
                              void* d_out, int out_size, void* d_ws, size_t ws_size,
                              hipStream_t stream) {
    const float* x  = (const float*)d_in[0];
    const float* W1 = (const float*)d_in[1];
    const float* b1 = (const float*)d_in[2];
    const float* W2 = (const float*)d_in[3];
    const float* b2 = (const float*)d_in[4];
    float* out = (float*)d_out;
    short* lwb = (short*)d_ws;   // 27648 bf16 = 55 KB

    lw_kernel<<<dim3(7, 16), 256, 0, stream>>>(W1, b1, W2, b2, lwb);
    meta_up_mfma<<<4 * 48 * 3, 192, 0, stream>>>(x, lwb, out);
}

// Round 7
// 126.762 us; speedup vs baseline: 1.7558x; 1.7558x over previous
//
#include <hip/hip_runtime.h>

// MetaUpSampler via bf16 MFMA — round 7 (= R5 + pinned B-fragments).
// GEMM view: out2d[m][po] = sum_{tap,c} x[n,c,h+di-1,w+dj-1] * lwb[tap][c][po]
// R6 lesson: acc[16]+Bfrag[18] exceeds register budget -> scratch thrash
//   (WRITE 190 MB). Tile stays at R5 size (1x64 strip, acc[4]).
// R5 lesson: compiler sinks Bfrag loads into the MFMA loop (VGPR=52), paying
//   ~18 x 300cyc serialized L2 latency per wave. Fix: empty inline-asm pin
//   after the loads forces VGPR residency; loads overlap the staging phase.

#define HH   192
#define WWD  192
#define SS   4
#define OC   3
#define PO   48
#define HID  256
#define W2LD 1728

typedef short  bf16x8 __attribute__((ext_vector_type(8)));
typedef float  f32x4  __attribute__((ext_vector_type(4)));

static __device__ __forceinline__ short f2bf(float f) {
    unsigned u = __float_as_uint(f);
    unsigned r = (u + 0x7fffu + ((u >> 16) & 1u)) >> 16;   // RNE
    return (short)r;
}

static __device__ __forceinline__ void pin(bf16x8& v) {
    asm volatile("" : "+v"(v));    // force VGPR residency; block load sinking
}

// ---------------- Stage A: MLP -> dynamic weights, bf16, [tap][po][c] -------
// Grid: dim3(7,16) x 256 threads. blockIdx.y = p; thread = one W2 column.
__global__ __launch_bounds__(256) void lw_kernel(
        const float* __restrict__ W1, const float* __restrict__ b1,
        const float* __restrict__ W2, const float* __restrict__ b2,
        short* __restrict__ lwb) {
    __shared__ float hlds[HID];
    const int tid = threadIdx.x;       // == hidden index h for the MLP part
    const int p   = blockIdx.y;
    {
        const float pi = (float)(p >> 2) * 0.25f;
        const float pj = (float)(p & 3) * 0.25f;
        const float v = 0.25f * W1[tid] + pi * W1[HID + tid] + pj * W1[2 * HID + tid]
                      + b1[tid];
        hlds[tid] = v > 0.f ? v : 0.f;
    }
    __syncthreads();

    const int col = blockIdx.x * 256 + tid;   // 0..1791 (guard at 1728)
    if (col < W2LD) {
        float a = 0.f;
#pragma unroll 32
        for (int h = 0; h < HID; ++h)
            a += hlds[h] * W2[h * W2LD + col];   // coalesced 4B + LDS broadcast
        const int o = col % 3, kc = col / 3;
        const int tap = kc % 9, c = kc / 9;
        lwb[(tap * PO + p * 3 + o) * 64 + c] = f2bf(a + b2[col]);
    }
}

// ---------------- Stage B: MFMA dynamic conv --------------------------------
__global__ __launch_bounds__(192, 3) void meta_up_mfma(
        const float* __restrict__ x, const short* __restrict__ lwb,
        float* __restrict__ out) {
    __shared__ __align__(16) short smem[3 * 66 * 64];   // 25,344 B
    short* xlds = smem;                    // [r][j][c], c in XOR'd 16B blocks
    float* obuf = (float*)smem;            // reused post-MFMA: 12 x 260 floats

    // XCD-band swizzle: 2304 strips = 8 XCDs x 288; contiguous (n,h) per XCD.
    const int strip = (blockIdx.x & 7) * 288 + (blockIdx.x >> 3);
    const int n   = strip / (HH * 3);
    const int rem = strip % (HH * 3);
    const int h   = rem / 3;
    const int wch = rem % 3;
    const int w0  = wch * 64;

    const int tid  = threadIdx.x;
    const int lane = tid & 63, wv = tid >> 6;     // wv = staging row AND po-tile
    const int quad = lane >> 4, l15 = lane & 15;

    // B fragments: one po-tile (16 po) per wave, all 9 taps x 2 K-chunks.
    // Issued first, pinned to registers -> latency overlaps staging below.
    bf16x8 Bfrag[18];
#pragma unroll
    for (int tap = 0; tap < 9; ++tap)
#pragma unroll
        for (int kc2 = 0; kc2 < 2; ++kc2)
            Bfrag[tap * 2 + kc2] = *(const bf16x8*)
                &lwb[(tap * PO + wv * 16 + l15) * 64 + kc2 * 32 + quad * 8];
#pragma unroll
    for (int i = 0; i < 18; ++i) pin(Bfrag[i]);

    // Stage x: wave wv handles row gr = h+wv-1. Lane = column j (coalesced);
    // gather 8 channels -> one ds_write_b128.
    {
        const int gr  = h + wv - 1;
        const bool rok = (unsigned)gr < (unsigned)HH;
        const int gc  = w0 - 1 + lane;
        const bool cok = rok && ((unsigned)gc < (unsigned)WWD);
        const float* __restrict__ xr =
            x + ((size_t)n * 64 * HH + (size_t)(rok ? gr : 0)) * WWD + (cok ? gc : 0);
#pragma unroll
        for (int cb = 0; cb < 8; ++cb) {
            bf16x8 pk;
#pragma unroll
            for (int cc = 0; cc < 8; ++cc) {
                const float vv = cok ? xr[(size_t)(cb * 8 + cc) * HH * WWD] : 0.f;
                pk[cc] = f2bf(vv);
            }
            *(bf16x8*)&xlds[(wv * 66 + lane) * 64 + ((cb ^ (lane & 7)) << 3)] = pk;
        }
        if (lane < 16) {                 // tail columns j = 64, 65
            const int jt = 64 + (lane >> 3);
            const int cb = lane & 7;
            const int gc2 = w0 - 1 + jt;
            const bool cok2 = rok && ((unsigned)gc2 < (unsigned)WWD);
            bf16x8 pk;
#pragma unroll
            for (int cc = 0; cc < 8; ++cc) {
                const float vv = cok2 ?
                    x[((size_t)(n * 64 + cb * 8 + cc) * HH + gr) * WWD + gc2] : 0.f;
                pk[cc] = f2bf(vv);
            }
            *(bf16x8*)&xlds[(wv * 66 + jt) * 64 + ((cb ^ (jt & 7)) << 3)] = pk;
        }
    }
    __syncthreads();

    // Main loop: FULLY unrolled 9 taps x 2 K-chunks x 4 m-tiles = 72 MFMAs.
    f32x4 acc[4];
#pragma unroll
    for (int mt = 0; mt < 4; ++mt) acc[mt] = (f32x4){0.f, 0.f, 0.f, 0.f};

#pragma unroll
    for (int tap = 0; tap < 9; ++tap) {
        const int di = tap / 3, dj = tap % 3;
#pragma unroll
        for (int kc2 = 0; kc2 < 2; ++kc2) {
            const bf16x8 b = Bfrag[tap * 2 + kc2];
#pragma unroll
            for (int mt = 0; mt < 4; ++mt) {
                const int col = mt * 16 + l15 + dj;           // 0..65
                const int blk = (kc2 * 4 + quad) ^ (col & 7);
                bf16x8 a = *(const bf16x8*)&xlds[(di * 66 + col) * 64 + (blk << 3)];
                acc[mt] = __builtin_amdgcn_mfma_f32_16x16x32_bf16(a, b, acc[mt], 0, 0, 0);
            }
        }
    }

    // Epilogue: transpose D through LDS -> full-line coalesced stores.
    __syncthreads();                       // all xlds reads complete
    {
        const int po = wv * 16 + l15;
        const int o  = po % 3;
        const int p  = po / 3;
        const int si = p >> 2, sj = p & 3;
        const int osi = o * 4 + si;
#pragma unroll
        for (int mt = 0; mt < 4; ++mt)
#pragma unroll
            for (int r4 = 0; r4 < 4; ++r4) {
                const int wl = mt * 16 + quad * 4 + r4;
                obuf[osi * 260 + wl * 4 + sj] = acc[mt][r4];
            }
    }
    __syncthreads();
    {
        const int osi = tid >> 4;          // 0..11
        const int c16 = tid & 15;
        const int o = osi >> 2, si = osi & 3;
        const size_t base =
            ((size_t)(n * OC + o) * (SS * HH) + (size_t)(SS * h + si)) * (SS * WWD)
            + (size_t)(4 * w0) + c16 * 16;
        const float* __restrict__ src = &obuf[osi * 260 + c16 * 16];
#pragma unroll
        for (int i = 0; i < 4; ++i)        // 64B contiguous per thread
            *(float4*)&out[base + i * 4] = *(const float4*)&src[i * 4];
    }
}

extern "C" void kernel_launch(void* const* d_in, const int* in_sizes, int n_in,
                              void* d_out, int out_size, void* d_ws, size_t ws_size,
                              hipStream_t stream) {
    const float* x  = (const float*)d_in[0];
    const float* W1 = (const float*)d_in[1];
    const float* b1 = (const float*)d_in[2];
    const float* W2 = (const float*)d_in[3];
    const float* b2 = (const float*)d_in[4];
    float* out = (float*)d_out;
    short* lwb = (short*)d_ws;   // 27648 bf16 = 55 KB

    lw_kernel<<<dim3(7, 16), 256, 0, stream>>>(W1, b1, W2, b2, lwb);
    meta_up_mfma<<<4 * HH * 3, 192, 0, stream>>>(x, lwb, out);
}